// Round 2
// baseline (83.438 us; speedup 1.0000x reference)
//
#include <hip/hip_runtime.h>
#include <math.h>

#define BLK 256
#define NX 8            // x-points per thread
#define XT 2            // x-tiles: 4096 / (BLK*NX)
#define NPTS 4096
#define UNITS 65536     // 2 dirs * 8 batches * 4096 points

// Kernel 1 (templated y-chunk length, compile-time trip counts):
// for each (dir, batch, x-tile, y-chunk) block, compute per x-point the min
// over the y-chunk of ||x-y||^2 via dist = 2*(x2/2 + min_y(y2/2 - x.y)).
// y-chunk staged in LDS as float4 (y0,y1,y2, 0.5*||y||^2); broadcast reads.
// Explicit 2-stage software pipeline: next 4 y's loaded before computing
// current 4. Min tree shaped to fuse into 2x v_min3_f32 per k per 4 y's.
template<int YLEN>
__global__ __launch_bounds__(BLK, 4) void chamfer_partial_t(
    const float* __restrict__ X, const float* __restrict__ Y,
    float* __restrict__ partial, float* __restrict__ out)
{
  constexpr int C = NPTS / YLEN;
  __shared__ float4 sh[YLEN];

  int lin = blockIdx.x;
  int c   = lin % C;  lin /= C;
  int xt  = lin % XT; lin /= XT;
  int b   = lin & 7;
  int dir = lin >> 3;

  const float* xs = (dir ? Y : X) + b * (NPTS * 3);
  const float* ys = (dir ? X : Y) + b * (NPTS * 3);

  // Zero d_out (re-poisoned to 0xAA before every launch). Kernel 2 runs
  // strictly after this dispatch on the stream, so ordering is safe.
  if (blockIdx.x == 0 && threadIdx.x < 8) out[threadIdx.x] = 0.0f;

  // Stage y chunk into LDS.
  int ybase = c * YLEN;
  for (int j = threadIdx.x; j < YLEN; j += BLK) {
    float y0 = ys[(ybase + j) * 3 + 0];
    float y1 = ys[(ybase + j) * 3 + 1];
    float y2 = ys[(ybase + j) * 3 + 2];
    sh[j] = make_float4(y0, y1, y2, 0.5f * (y0 * y0 + y1 * y1 + y2 * y2));
  }
  __syncthreads();

  // This thread's 8 x-points (24 contiguous floats, 16B-aligned).
  int x0i = xt * (BLK * NX) + threadIdx.x * NX;
  float xf[NX * 3];
  {
    const float4* xp = reinterpret_cast<const float4*>(xs + x0i * 3);
    #pragma unroll
    for (int i = 0; i < 6; ++i) {
      float4 p = xp[i];
      xf[i * 4 + 0] = p.x; xf[i * 4 + 1] = p.y;
      xf[i * 4 + 2] = p.z; xf[i * 4 + 3] = p.w;
    }
  }
  float n0[NX], n1[NX], n2[NX], x2h[NX], gm[NX];
  #pragma unroll
  for (int k = 0; k < NX; ++k) {
    float a = xf[k * 3 + 0], bb = xf[k * 3 + 1], cc = xf[k * 3 + 2];
    n0[k] = -a; n1[k] = -bb; n2[k] = -cc;
    x2h[k] = 0.5f * (a * a + bb * bb + cc * cc);
    gm[k] = __builtin_inff();
  }

  // Process 4 y's against all 8 x's: 12 FMA + 2 v_min3 per k.
  auto proc = [&](const float4& p0, const float4& p1,
                  const float4& p2, const float4& p3) {
    #pragma unroll
    for (int k = 0; k < NX; ++k) {
      float ga = fmaf(n0[k], p0.x, fmaf(n1[k], p0.y, fmaf(n2[k], p0.z, p0.w)));
      float gb = fmaf(n0[k], p1.x, fmaf(n1[k], p1.y, fmaf(n2[k], p1.z, p1.w)));
      float gc = fmaf(n0[k], p2.x, fmaf(n1[k], p2.y, fmaf(n2[k], p2.z, p2.w)));
      float gd = fmaf(n0[k], p3.x, fmaf(n1[k], p3.y, fmaf(n2[k], p3.z, p3.w)));
      float m  = fminf(fminf(ga, gb), gc);       // v_min3
      gm[k] = fminf(fminf(m, gd), gm[k]);        // v_min3
    }
  };

  // 2-stage pipeline: prefetch j+4..j+7 before computing j..j+3.
  float4 c0 = sh[0], c1 = sh[1], c2 = sh[2], c3 = sh[3];
  #pragma unroll 2
  for (int j = 4; j < YLEN; j += 4) {
    float4 t0 = sh[j], t1 = sh[j + 1], t2 = sh[j + 2], t3 = sh[j + 3];
    proc(c0, c1, c2, c3);
    c0 = t0; c1 = t1; c2 = t2; c3 = t3;
  }
  proc(c0, c1, c2, c3);

  float res[NX];
  #pragma unroll
  for (int k = 0; k < NX; ++k) res[k] = 2.0f * (x2h[k] + gm[k]);

  float* dst = partial + (size_t)c * UNITS + dir * 32768 + b * 4096 + x0i;
  float4* d4 = reinterpret_cast<float4*>(dst);
  d4[0] = make_float4(res[0], res[1], res[2], res[3]);
  d4[1] = make_float4(res[4], res[5], res[6], res[7]);
}

// Kernel 2: min across C chunks per point, block-reduce sums, one atomicAdd
// per block into out[b]. Grid: 8 batches x 32 slices of 256 points.
__global__ __launch_bounds__(BLK, 4) void chamfer_reduce_kernel(
    const float* __restrict__ partial, float* __restrict__ out, int C)
{
  int b = blockIdx.x >> 5;
  int s = blockIdx.x & 31;
  int i = s * BLK + threadIdx.x;   // 0..8191 within batch (both directions)
  int dir = i >> 12;
  int xi  = i & 4095;
  int unit = dir * 32768 + b * 4096 + xi;
  // 4 independent min chains to hide strided-load latency.
  float v0 =  __builtin_inff(), v1 = v0, v2 = v0, v3 = v0;
  int c = 0;
  for (; c + 4 <= C; c += 4) {
    v0 = fminf(v0, partial[(size_t)(c + 0) * UNITS + unit]);
    v1 = fminf(v1, partial[(size_t)(c + 1) * UNITS + unit]);
    v2 = fminf(v2, partial[(size_t)(c + 2) * UNITS + unit]);
    v3 = fminf(v3, partial[(size_t)(c + 3) * UNITS + unit]);
  }
  for (; c < C; ++c) v0 = fminf(v0, partial[(size_t)c * UNITS + unit]);
  float v = fminf(fminf(v0, v1), fminf(v2, v3));
  #pragma unroll
  for (int off = 32; off > 0; off >>= 1) v += __shfl_down(v, off, 64);
  __shared__ float wsum[BLK / 64];
  if ((threadIdx.x & 63) == 0) wsum[threadIdx.x >> 6] = v;
  __syncthreads();
  if (threadIdx.x == 0) {
    float t = wsum[0] + wsum[1] + wsum[2] + wsum[3];
    atomicAdd(&out[b], t * (1.0f / 4096.0f));
  }
}

// Fallback (workspace too small): full y range per block, direct reduction.
__global__ __launch_bounds__(BLK, 2) void chamfer_direct_kernel(
    const float* __restrict__ X, const float* __restrict__ Y,
    float* __restrict__ out)
{
  extern __shared__ float4 shd[];
  int lin = blockIdx.x;
  int xt  = lin % XT; lin /= XT;
  int b   = lin & 7;
  int dir = lin >> 3;
  const float* xs = (dir ? Y : X) + b * (NPTS * 3);
  const float* ys = (dir ? X : Y) + b * (NPTS * 3);

  for (int j = threadIdx.x; j < NPTS; j += BLK) {
    float y0 = ys[j * 3 + 0], y1 = ys[j * 3 + 1], y2 = ys[j * 3 + 2];
    shd[j] = make_float4(y0, y1, y2, 0.5f * (y0 * y0 + y1 * y1 + y2 * y2));
  }
  __syncthreads();

  int x0i = xt * (BLK * NX) + threadIdx.x * NX;
  float xf[NX * 3];
  const float4* xp = reinterpret_cast<const float4*>(xs + x0i * 3);
  #pragma unroll
  for (int i = 0; i < 6; ++i) {
    float4 p = xp[i];
    xf[i * 4 + 0] = p.x; xf[i * 4 + 1] = p.y;
    xf[i * 4 + 2] = p.z; xf[i * 4 + 3] = p.w;
  }
  float n0[NX], n1[NX], n2[NX], x2h[NX], gm[NX];
  #pragma unroll
  for (int k = 0; k < NX; ++k) {
    float a = xf[k * 3 + 0], bb = xf[k * 3 + 1], cc = xf[k * 3 + 2];
    n0[k] = -a; n1[k] = -bb; n2[k] = -cc;
    x2h[k] = 0.5f * (a * a + bb * bb + cc * cc);
    gm[k] = __builtin_inff();
  }
  for (int j = 0; j < NPTS; j += 4) {
    float4 p0 = shd[j], p1 = shd[j + 1], p2 = shd[j + 2], p3 = shd[j + 3];
    #pragma unroll
    for (int k = 0; k < NX; ++k) {
      float ga = fmaf(n0[k], p0.x, fmaf(n1[k], p0.y, fmaf(n2[k], p0.z, p0.w)));
      float gb = fmaf(n0[k], p1.x, fmaf(n1[k], p1.y, fmaf(n2[k], p1.z, p1.w)));
      float gc = fmaf(n0[k], p2.x, fmaf(n1[k], p2.y, fmaf(n2[k], p2.z, p2.w)));
      float gd = fmaf(n0[k], p3.x, fmaf(n1[k], p3.y, fmaf(n2[k], p3.z, p3.w)));
      float m  = fminf(fminf(ga, gb), gc);
      gm[k] = fminf(fminf(m, gd), gm[k]);
    }
  }
  float v = 0.0f;
  #pragma unroll
  for (int k = 0; k < NX; ++k) v += 2.0f * (x2h[k] + gm[k]);
  #pragma unroll
  for (int off = 32; off > 0; off >>= 1) v += __shfl_down(v, off, 64);
  __syncthreads();
  float* red = reinterpret_cast<float*>(shd);
  if ((threadIdx.x & 63) == 0) red[threadIdx.x >> 6] = v;
  __syncthreads();
  if (threadIdx.x == 0) {
    float s = red[0] + red[1] + red[2] + red[3];
    atomicAdd(&out[b], s * (1.0f / 4096.0f));
  }
}

__global__ void zero_out_kernel(float* out)
{
  if (threadIdx.x < 8) out[threadIdx.x] = 0.0f;
}

extern "C" void kernel_launch(void* const* d_in, const int* in_sizes, int n_in,
                              void* d_out, int out_size, void* d_ws, size_t ws_size,
                              hipStream_t stream)
{
  const float* X = (const float*)d_in[0];
  const float* Y = (const float*)d_in[1];
  float* out = (float*)d_out;

  if (ws_size >= (size_t)32 * UNITS * sizeof(float)) {
    // C=32, YLEN=128: grid 1024 -> 4 blocks/CU -> 4 waves/SIMD.
    chamfer_partial_t<128><<<2 * 8 * XT * 32, BLK, 0, stream>>>(
        X, Y, (float*)d_ws, out);
    chamfer_reduce_kernel<<<256, BLK, 0, stream>>>((const float*)d_ws, out, 32);
  } else if (ws_size >= (size_t)8 * UNITS * sizeof(float)) {
    // C=8, YLEN=512: grid 256.
    chamfer_partial_t<512><<<2 * 8 * XT * 8, BLK, 0, stream>>>(
        X, Y, (float*)d_ws, out);
    chamfer_reduce_kernel<<<256, BLK, 0, stream>>>((const float*)d_ws, out, 8);
  } else {
    zero_out_kernel<<<1, 64, 0, stream>>>(out);
    chamfer_direct_kernel<<<2 * 8 * XT, BLK, NPTS * sizeof(float4), stream>>>(
        X, Y, out);
  }
}